// Round 12
// baseline (245.523 us; speedup 1.0000x reference)
//
#include <hip/hip_runtime.h>
#include <hip/hip_fp16.h>

#define N_NODES 50000
#define K 32
#define NSEL 16
#define D 128
#define DOUT 64
#define NTILES (N_NODES / 16)  // 3125 MFMA node-tiles

typedef __attribute__((ext_vector_type(8))) _Float16 half8;
typedef __attribute__((ext_vector_type(4))) float floatx4;
typedef __attribute__((ext_vector_type(2))) float floatx2;

__device__ __forceinline__ unsigned int pack_h2(float a, float b) {
  union { __half2 h; unsigned int u; } c;
  c.h = __floats2half2_rn(a, b);
  return c.u;
}
__device__ __forceinline__ float fast_tanh(float x) {
  // 1 - 2/(1+e^{2x}). Exact at +/-inf.
  float e = __expf(2.f * x);
  return 1.f - __fdividef(2.f, 1.f + e);
}

// Kernel A: mlp2[n] = tanh(feat[n] @ W_mlp + b_mlp) (C=2), feat8 = fp8(feat).
// TWO nodes per wave. libm tanhf — mlp2 feeds top-k; fast tanh flips ties.
__global__ __launch_bounds__(256) void mlp_kernel(
    const float* __restrict__ feat, const float* __restrict__ Wm,
    const float* __restrict__ bm, float2* __restrict__ mlp2,
    unsigned char* __restrict__ feat8 /* [N][D] fp8 e4m3, 128 B rows */) {
  const int wid = (blockIdx.x * blockDim.x + threadIdx.x) >> 6;  // 0..24999
  const int lane = threadIdx.x & 63;
  const int sub = lane & 31;
  const int n = wid * 2 + (lane >> 5);

  float4 f = *(const float4*)(feat + (size_t)n * D + sub * 4);
  float4 w01 = *(const float4*)(Wm + sub * 8);
  float4 w23 = *(const float4*)(Wm + sub * 8 + 4);
  float p0 = f.x * w01.x + f.y * w01.z + f.z * w23.x + f.w * w23.z;
  float p1 = f.x * w01.y + f.y * w01.w + f.z * w23.y + f.w * w23.w;
#pragma unroll
  for (int off = 16; off; off >>= 1) {  // stays within the 32-lane half
    p0 += __shfl_xor(p0, off);
    p1 += __shfl_xor(p1, off);
  }
  int pk8 = __builtin_amdgcn_cvt_pk_fp8_f32(f.x, f.y, 0, false);
  pk8 = __builtin_amdgcn_cvt_pk_fp8_f32(f.z, f.w, pk8, true);
  *(unsigned int*)(feat8 + ((size_t)n << 7) + (sub << 2)) = (unsigned int)pk8;
  if (sub == 0) {
    mlp2[n] = make_float2(tanhf(p0 + bm[0]), tanhf(p1 + bm[1]));
  }
}

// Kernel B: FOUR nodes per wave (16 lanes each; lane owns 8 dims, 2 edges).
// Rank: one bpermute broadcast per j serves all 4 groups; 2 u64-key compares
// per lane (key=(bits(d)<<32)|j — lexicographic < is EXACTLY top_k's
// tie-break). Selection: masked ds_write scatter to per-wave LDS table,
// wave_barrier, then group-uniform broadcast ds_read. Gather: uint2 fp8
// loads (8 dims/lane), f32 pk accumulation in t-order (bit-identical).
__global__ __launch_bounds__(256, 6) void care_kernel(
    const float* __restrict__ feat, const unsigned char* __restrict__ feat8,
    const float2* __restrict__ mlp2, const int* __restrict__ nbr0,
    const int* __restrict__ nbr1, const int* __restrict__ nbr2,
    unsigned int* __restrict__ hfw /* aliases d_out; [N][64] words */) {
  __shared__ int selbuf[4][4][3][17];  // [wave][grp][etype][16+pad] = 3.3 KB
  const int lane = threadIdx.x & 63;
  const int w = threadIdx.x >> 6;
  const int grp = lane >> 4;
  const int sli = lane & 15;
  const int gb = (lane & 48) << 2;  // DS byte addr of group's lane 0
  const int wid = blockIdx.x * 4 + w;  // 0..12499
  const int n = wid * 4 + grp;

  const float2 my = mlp2[n];
  // residual: 8 dims [8*sli, 8*sli+8)
  float4 ra = *(const float4*)(feat + (size_t)n * D + sli * 8);
  float4 rb = *(const float4*)(feat + (size_t)n * D + sli * 8 + 4);

  // Phase 1: 2 edges per lane per etype
  const int srcA0 = nbr0[n * K + sli], srcB0 = nbr0[n * K + sli + 16];
  const int srcA1 = nbr1[n * K + sli], srcB1 = nbr1[n * K + sli + 16];
  const int srcA2 = nbr2[n * K + sli], srcB2 = nbr2[n * K + sli + 16];
  const float2 mA0 = mlp2[srcA0], mB0 = mlp2[srcB0];
  const float2 mA1 = mlp2[srcA1], mB1 = mlp2[srcB1];
  const float2 mA2 = mlp2[srcA2], mB2 = mlp2[srcB2];
  const int bA0 = __float_as_int(fabsf(mA0.x - my.x) + fabsf(mA0.y - my.y));
  const int bB0 = __float_as_int(fabsf(mB0.x - my.x) + fabsf(mB0.y - my.y));
  const int bA1 = __float_as_int(fabsf(mA1.x - my.x) + fabsf(mA1.y - my.y));
  const int bB1 = __float_as_int(fabsf(mB1.x - my.x) + fabsf(mB1.y - my.y));
  const int bA2 = __float_as_int(fabsf(mA2.x - my.x) + fabsf(mA2.y - my.y));
  const int bB2 = __float_as_int(fabsf(mB2.x - my.x) + fabsf(mB2.y - my.y));
  const unsigned long long kA0 =
      ((unsigned long long)(unsigned)bA0 << 32) | (unsigned)sli;
  const unsigned long long kB0 =
      ((unsigned long long)(unsigned)bB0 << 32) | (unsigned)(sli + 16);
  const unsigned long long kA1 =
      ((unsigned long long)(unsigned)bA1 << 32) | (unsigned)sli;
  const unsigned long long kB1 =
      ((unsigned long long)(unsigned)bB1 << 32) | (unsigned)(sli + 16);
  const unsigned long long kA2 =
      ((unsigned long long)(unsigned)bA2 << 32) | (unsigned)sli;
  const unsigned long long kB2 =
      ((unsigned long long)(unsigned)bB2 << 32) | (unsigned)(sli + 16);

  // Phase 2: rank — one group-broadcast per j serves all 4 nodes
  int cA0 = 0, cB0 = 0, cA1 = 0, cB1 = 0, cA2 = 0, cB2 = 0;
#pragma unroll
  for (int j = 0; j < K; ++j) {
    const int a = gb + ((j & 15) << 2);
    const unsigned j0 = (unsigned)__builtin_amdgcn_ds_bpermute(
        a, (j < 16) ? bA0 : bB0);
    const unsigned j1 = (unsigned)__builtin_amdgcn_ds_bpermute(
        a, (j < 16) ? bA1 : bB1);
    const unsigned j2 = (unsigned)__builtin_amdgcn_ds_bpermute(
        a, (j < 16) ? bA2 : bB2);
    const unsigned long long kj0 = ((unsigned long long)j0 << 32) | (unsigned)j;
    const unsigned long long kj1 = ((unsigned long long)j1 << 32) | (unsigned)j;
    const unsigned long long kj2 = ((unsigned long long)j2 << 32) | (unsigned)j;
    cA0 += kj0 < kA0;  cB0 += kj0 < kB0;
    cA1 += kj1 < kA1;  cB1 += kj1 < kB1;
    cA2 += kj2 < kA2;  cB2 += kj2 < kB2;
  }

  // Selection scatter: ranks unique per node; exactly 16 are < NSEL.
  if (cA0 < NSEL) selbuf[w][grp][0][cA0] = srcA0;
  if (cB0 < NSEL) selbuf[w][grp][0][cB0] = srcB0;
  if (cA1 < NSEL) selbuf[w][grp][1][cA1] = srcA1;
  if (cB1 < NSEL) selbuf[w][grp][1][cB1] = srcB1;
  if (cA2 < NSEL) selbuf[w][grp][2][cA2] = srcA2;
  if (cB2 < NSEL) selbuf[w][grp][2][cB2] = srcB2;
  __builtin_amdgcn_wave_barrier();  // order LDS scatter before broadcast reads

  // Phase 3: gather — group-uniform sel reads, uint2 fp8 loads, f32 pk accum
  const unsigned off8 = (unsigned)sli << 3;
  floatx2 A0[4] = {{0.f, 0.f}, {0.f, 0.f}, {0.f, 0.f}, {0.f, 0.f}};
  floatx2 A1[4] = {{0.f, 0.f}, {0.f, 0.f}, {0.f, 0.f}, {0.f, 0.f}};
  floatx2 A2[4] = {{0.f, 0.f}, {0.f, 0.f}, {0.f, 0.f}, {0.f, 0.f}};
#pragma unroll
  for (int t = 0; t < NSEL; ++t) {
    const int s0 = selbuf[w][grp][0][t];
    const int s1 = selbuf[w][grp][1][t];
    const int s2 = selbuf[w][grp][2][t];
    uint2 u0 = *(const uint2*)(feat8 + (((unsigned)s0 << 7) | off8));
    uint2 u1 = *(const uint2*)(feat8 + (((unsigned)s1 << 7) | off8));
    uint2 u2 = *(const uint2*)(feat8 + (((unsigned)s2 << 7) | off8));
    A0[0] += __builtin_amdgcn_cvt_pk_f32_fp8(u0.x, false);
    A0[1] += __builtin_amdgcn_cvt_pk_f32_fp8(u0.x, true);
    A0[2] += __builtin_amdgcn_cvt_pk_f32_fp8(u0.y, false);
    A0[3] += __builtin_amdgcn_cvt_pk_f32_fp8(u0.y, true);
    A1[0] += __builtin_amdgcn_cvt_pk_f32_fp8(u1.x, false);
    A1[1] += __builtin_amdgcn_cvt_pk_f32_fp8(u1.x, true);
    A1[2] += __builtin_amdgcn_cvt_pk_f32_fp8(u1.y, false);
    A1[3] += __builtin_amdgcn_cvt_pk_f32_fp8(u1.y, true);
    A2[0] += __builtin_amdgcn_cvt_pk_f32_fp8(u2.x, false);
    A2[1] += __builtin_amdgcn_cvt_pk_f32_fp8(u2.x, true);
    A2[2] += __builtin_amdgcn_cvt_pk_f32_fp8(u2.y, false);
    A2[3] += __builtin_amdgcn_cvt_pk_f32_fp8(u2.y, true);
  }

  // Epilogue: acc[d] = feat + sum_e 0.5*tanh(mean_e[d]); then tanh, fp16 pack
  float accv[8] = {ra.x, ra.y, ra.z, ra.w, rb.x, rb.y, rb.z, rb.w};
#pragma unroll
  for (int q = 0; q < 4; ++q) {
    accv[2 * q] += 0.5f * fast_tanh(A0[q].x * (1.f / NSEL));
    accv[2 * q + 1] += 0.5f * fast_tanh(A0[q].y * (1.f / NSEL));
    accv[2 * q] += 0.5f * fast_tanh(A1[q].x * (1.f / NSEL));
    accv[2 * q + 1] += 0.5f * fast_tanh(A1[q].y * (1.f / NSEL));
    accv[2 * q] += 0.5f * fast_tanh(A2[q].x * (1.f / NSEL));
    accv[2 * q + 1] += 0.5f * fast_tanh(A2[q].y * (1.f / NSEL));
  }
  uint4 p;
  p.x = pack_h2(fast_tanh(accv[0]), fast_tanh(accv[1]));
  p.y = pack_h2(fast_tanh(accv[2]), fast_tanh(accv[3]));
  p.z = pack_h2(fast_tanh(accv[4]), fast_tanh(accv[5]));
  p.w = pack_h2(fast_tanh(accv[6]), fast_tanh(accv[7]));
  *(uint4*)(hfw + n * (D / 2) + sli * 4) = p;  // fp16 h row, 256 B/node
}

// Kernel C: out[50000x64] = h[50000x128] @ W_lin + b_lin via fp16 MFMA.
// h read fp16-packed from d_out rows, overwritten in place (each wave reads
// its full 16-row tile before storing). A: m=lane&15, k=(lane>>4)*8+j.
// C: n=lane&15, m=(lane>>4)*4+reg (m89-verified).
__global__ __launch_bounds__(256) void gemm_kernel(
    const unsigned int* __restrict__ hfw, const float* __restrict__ Wl,
    const float* __restrict__ bl, float* __restrict__ out) {
  __shared__ _Float16 sB[16 * 64 * 8];  // 16 KB: [kk*4+nt][lane][8]

  for (int w = threadIdx.x; w < 4096; w += blockDim.x) {
    int f = w >> 8, l = (w >> 2) & 63, j2 = w & 3;
    int kk = f >> 2, nt = f & 3;
    int k = kk * 32 + ((l >> 4) << 3) + 2 * j2;
    int nn = nt * 16 + (l & 15);
    ((unsigned int*)sB)[w] = pack_h2(Wl[k * DOUT + nn], Wl[(k + 1) * DOUT + nn]);
  }
  __syncthreads();

  const int lane = threadIdx.x & 63;
  const int tile = blockIdx.x * 4 + (threadIdx.x >> 6);
  if (tile >= NTILES) return;
  const int m0 = tile * 16;

  floatx4 acc[4];
#pragma unroll
  for (int nt = 0; nt < 4; ++nt) {
    float bn = bl[nt * 16 + (lane & 15)];
    acc[nt] = (floatx4){bn, bn, bn, bn};
  }
  const _Float16* hf = (const _Float16*)hfw;
#pragma unroll
  for (int kk = 0; kk < 4; ++kk) {
    half8 a = *(const half8*)(hf + (size_t)(m0 + (lane & 15)) * D + kk * 32 +
                              ((lane >> 4) << 3));
#pragma unroll
    for (int nt = 0; nt < 4; ++nt) {
      half8 bfr = *(const half8*)(sB + ((kk * 4 + nt) * 64 + lane) * 8);
      acc[nt] = __builtin_amdgcn_mfma_f32_16x16x32_f16(a, bfr, acc[nt], 0, 0, 0);
    }
  }
#pragma unroll
  for (int nt = 0; nt < 4; ++nt) {
#pragma unroll
    for (int r = 0; r < 4; ++r) {
      int m = m0 + ((lane >> 4) << 2) + r;
      out[(size_t)m * DOUT + nt * 16 + (lane & 15)] = acc[nt][r];
    }
  }
}

extern "C" void kernel_launch(void* const* d_in, const int* in_sizes, int n_in,
                              void* d_out, int out_size, void* d_ws,
                              size_t ws_size, hipStream_t stream) {
  const float* feat = (const float*)d_in[0];
  const float* Wm = (const float*)d_in[1];
  const float* bm = (const float*)d_in[2];
  const float* Wl = (const float*)d_in[3];
  const float* bl = (const float*)d_in[4];
  const int* nbr0 = (const int*)d_in[5];
  const int* nbr1 = (const int*)d_in[6];
  const int* nbr2 = (const int*)d_in[7];
  float* out = (float*)d_out;
  float2* mlp2 = (float2*)d_ws;                                       // 400 KB
  unsigned char* feat8 = (unsigned char*)d_ws + (512 << 10);          // 6.4 MB

  mlp_kernel<<<N_NODES / 8, 256, 0, stream>>>(feat, Wm, bm, mlp2, feat8);
  care_kernel<<<N_NODES / 16, 256, 0, stream>>>(feat, feat8, mlp2, nbr0, nbr1,
                                                nbr2, (unsigned int*)d_out);
  gemm_kernel<<<(NTILES + 3) / 4, 256, 0, stream>>>((const unsigned int*)d_out,
                                                    Wl, bl, out);
}

// Round 13
// 236.003 us; speedup vs baseline: 1.0403x; 1.0403x over previous
//
#include <hip/hip_runtime.h>
#include <hip/hip_fp16.h>

#define N_NODES 50000
#define K 32
#define NSEL 16
#define D 128
#define DOUT 64
#define NTILES (N_NODES / 16)  // 3125 MFMA node-tiles

typedef __attribute__((ext_vector_type(8))) _Float16 half8;
typedef __attribute__((ext_vector_type(4))) float floatx4;
typedef __attribute__((ext_vector_type(2))) float floatx2;

__device__ __forceinline__ unsigned int pack_h2(float a, float b) {
  union { __half2 h; unsigned int u; } c;
  c.h = __floats2half2_rn(a, b);
  return c.u;
}
__device__ __forceinline__ float fast_tanh(float x) {
  // 1 - 2/(1+e^{2x}). Exact at +/-inf.
  float e = __expf(2.f * x);
  return 1.f - __fdividef(2.f, 1.f + e);
}

// Kernel A: mlp2[n] = tanh(feat[n] @ W_mlp + b_mlp) (C=2), feat8 = fp8(feat).
// TWO nodes per wave. libm tanhf — mlp2 feeds top-k; fast tanh flips ties.
__global__ __launch_bounds__(256) void mlp_kernel(
    const float* __restrict__ feat, const float* __restrict__ Wm,
    const float* __restrict__ bm, float2* __restrict__ mlp2,
    unsigned char* __restrict__ feat8 /* [N][D] fp8 e4m3, 128 B rows */) {
  const int wid = (blockIdx.x * blockDim.x + threadIdx.x) >> 6;  // 0..24999
  const int lane = threadIdx.x & 63;
  const int sub = lane & 31;
  const int n = wid * 2 + (lane >> 5);

  float4 f = *(const float4*)(feat + (size_t)n * D + sub * 4);
  float4 w01 = *(const float4*)(Wm + sub * 8);
  float4 w23 = *(const float4*)(Wm + sub * 8 + 4);
  float p0 = f.x * w01.x + f.y * w01.z + f.z * w23.x + f.w * w23.z;
  float p1 = f.x * w01.y + f.y * w01.w + f.z * w23.y + f.w * w23.w;
#pragma unroll
  for (int off = 16; off; off >>= 1) {  // stays within the 32-lane half
    p0 += __shfl_xor(p0, off);
    p1 += __shfl_xor(p1, off);
  }
  int pk8 = __builtin_amdgcn_cvt_pk_fp8_f32(f.x, f.y, 0, false);
  pk8 = __builtin_amdgcn_cvt_pk_fp8_f32(f.z, f.w, pk8, true);
  *(unsigned int*)(feat8 + ((size_t)n << 7) + (sub << 2)) = (unsigned int)pk8;
  if (sub == 0) {
    mlp2[n] = make_float2(tanhf(p0 + bm[0]), tanhf(p1 + bm[1]));
  }
}

// Kernel B: FOUR nodes per wave (16 lanes each; lane owns 8 dims, 2 edges).
// Rank: one bpermute broadcast per j serves all 4 groups; u64-key compares
// (key=(bits(d)<<32)|j — lexicographic < is EXACTLY top_k's tie-break).
// Selection: masked ds_write scatter to per-wave LDS table, wave_barrier,
// group-uniform broadcast ds_read. Gather: uint2 fp8 loads (8 dims/lane),
// f32 pk accumulation in t-order (bit-identical to R11).
// ALL accumulators are NAMED SCALARS — no arrays — to avoid scratch (R12
// lesson: runtime-indexed vector arrays -> localMem -> 475 MB HBM writes).
__global__ __launch_bounds__(256, 6) void care_kernel(
    const float* __restrict__ feat, const unsigned char* __restrict__ feat8,
    const float2* __restrict__ mlp2, const int* __restrict__ nbr0,
    const int* __restrict__ nbr1, const int* __restrict__ nbr2,
    unsigned int* __restrict__ hfw /* aliases d_out; [N][64] words */) {
  __shared__ int selbuf[4][4][3][17];  // [wave][grp][etype][16+pad] = 3.3 KB
  const int lane = threadIdx.x & 63;
  const int w = threadIdx.x >> 6;
  const int grp = lane >> 4;
  const int sli = lane & 15;
  const int gb = (lane & 48) << 2;  // DS byte addr of group's lane 0
  const int wid = blockIdx.x * 4 + w;  // 0..12499
  const int n = wid * 4 + grp;

  const float2 my = mlp2[n];
  // residual: 8 dims [8*sli, 8*sli+8)
  const float4 ra = *(const float4*)(feat + (size_t)n * D + sli * 8);
  const float4 rb = *(const float4*)(feat + (size_t)n * D + sli * 8 + 4);

  // Phase 1: 2 edges per lane per etype
  const int srcA0 = nbr0[n * K + sli], srcB0 = nbr0[n * K + sli + 16];
  const int srcA1 = nbr1[n * K + sli], srcB1 = nbr1[n * K + sli + 16];
  const int srcA2 = nbr2[n * K + sli], srcB2 = nbr2[n * K + sli + 16];
  const float2 mA0 = mlp2[srcA0], mB0 = mlp2[srcB0];
  const float2 mA1 = mlp2[srcA1], mB1 = mlp2[srcB1];
  const float2 mA2 = mlp2[srcA2], mB2 = mlp2[srcB2];
  const int bA0 = __float_as_int(fabsf(mA0.x - my.x) + fabsf(mA0.y - my.y));
  const int bB0 = __float_as_int(fabsf(mB0.x - my.x) + fabsf(mB0.y - my.y));
  const int bA1 = __float_as_int(fabsf(mA1.x - my.x) + fabsf(mA1.y - my.y));
  const int bB1 = __float_as_int(fabsf(mB1.x - my.x) + fabsf(mB1.y - my.y));
  const int bA2 = __float_as_int(fabsf(mA2.x - my.x) + fabsf(mA2.y - my.y));
  const int bB2 = __float_as_int(fabsf(mB2.x - my.x) + fabsf(mB2.y - my.y));
  const unsigned long long kA0 =
      ((unsigned long long)(unsigned)bA0 << 32) | (unsigned)sli;
  const unsigned long long kB0 =
      ((unsigned long long)(unsigned)bB0 << 32) | (unsigned)(sli + 16);
  const unsigned long long kA1 =
      ((unsigned long long)(unsigned)bA1 << 32) | (unsigned)sli;
  const unsigned long long kB1 =
      ((unsigned long long)(unsigned)bB1 << 32) | (unsigned)(sli + 16);
  const unsigned long long kA2 =
      ((unsigned long long)(unsigned)bA2 << 32) | (unsigned)sli;
  const unsigned long long kB2 =
      ((unsigned long long)(unsigned)bB2 << 32) | (unsigned)(sli + 16);

  // Phase 2: rank — one group-broadcast per j serves all 4 nodes.
  // j is a literal in each unrolled step, so (j<16) resolves at compile time.
  int cA0 = 0, cB0 = 0, cA1 = 0, cB1 = 0, cA2 = 0, cB2 = 0;
#pragma unroll
  for (int j = 0; j < K; ++j) {
    const int a = gb + ((j & 15) << 2);
    const unsigned j0 = (unsigned)__builtin_amdgcn_ds_bpermute(
        a, (j < 16) ? bA0 : bB0);
    const unsigned j1 = (unsigned)__builtin_amdgcn_ds_bpermute(
        a, (j < 16) ? bA1 : bB1);
    const unsigned j2 = (unsigned)__builtin_amdgcn_ds_bpermute(
        a, (j < 16) ? bA2 : bB2);
    const unsigned long long kj0 = ((unsigned long long)j0 << 32) | (unsigned)j;
    const unsigned long long kj1 = ((unsigned long long)j1 << 32) | (unsigned)j;
    const unsigned long long kj2 = ((unsigned long long)j2 << 32) | (unsigned)j;
    cA0 += kj0 < kA0;  cB0 += kj0 < kB0;
    cA1 += kj1 < kA1;  cB1 += kj1 < kB1;
    cA2 += kj2 < kA2;  cB2 += kj2 < kB2;
  }

  // Selection scatter: ranks unique per node; exactly 16 are < NSEL.
  if (cA0 < NSEL) selbuf[w][grp][0][cA0] = srcA0;
  if (cB0 < NSEL) selbuf[w][grp][0][cB0] = srcB0;
  if (cA1 < NSEL) selbuf[w][grp][1][cA1] = srcA1;
  if (cB1 < NSEL) selbuf[w][grp][1][cB1] = srcB1;
  if (cA2 < NSEL) selbuf[w][grp][2][cA2] = srcA2;
  if (cB2 < NSEL) selbuf[w][grp][2][cB2] = srcB2;
  __builtin_amdgcn_wave_barrier();  // order LDS scatter before broadcast reads

  // Phase 3: gather — group-uniform sel reads, uint2 fp8 loads, named-scalar
  // f32 pk accumulation (NO arrays).
  const unsigned off8 = (unsigned)sli << 3;
  floatx2 A00 = {0.f, 0.f}, A01 = {0.f, 0.f}, A02 = {0.f, 0.f}, A03 = {0.f, 0.f};
  floatx2 A10 = {0.f, 0.f}, A11 = {0.f, 0.f}, A12 = {0.f, 0.f}, A13 = {0.f, 0.f};
  floatx2 A20 = {0.f, 0.f}, A21 = {0.f, 0.f}, A22 = {0.f, 0.f}, A23 = {0.f, 0.f};
#pragma unroll
  for (int t = 0; t < NSEL; ++t) {
    const int s0 = selbuf[w][grp][0][t];
    const int s1 = selbuf[w][grp][1][t];
    const int s2 = selbuf[w][grp][2][t];
    const uint2 u0 = *(const uint2*)(feat8 + (((unsigned)s0 << 7) | off8));
    const uint2 u1 = *(const uint2*)(feat8 + (((unsigned)s1 << 7) | off8));
    const uint2 u2 = *(const uint2*)(feat8 + (((unsigned)s2 << 7) | off8));
    A00 += __builtin_amdgcn_cvt_pk_f32_fp8(u0.x, false);
    A01 += __builtin_amdgcn_cvt_pk_f32_fp8(u0.x, true);
    A02 += __builtin_amdgcn_cvt_pk_f32_fp8(u0.y, false);
    A03 += __builtin_amdgcn_cvt_pk_f32_fp8(u0.y, true);
    A10 += __builtin_amdgcn_cvt_pk_f32_fp8(u1.x, false);
    A11 += __builtin_amdgcn_cvt_pk_f32_fp8(u1.x, true);
    A12 += __builtin_amdgcn_cvt_pk_f32_fp8(u1.y, false);
    A13 += __builtin_amdgcn_cvt_pk_f32_fp8(u1.y, true);
    A20 += __builtin_amdgcn_cvt_pk_f32_fp8(u2.x, false);
    A21 += __builtin_amdgcn_cvt_pk_f32_fp8(u2.x, true);
    A22 += __builtin_amdgcn_cvt_pk_f32_fp8(u2.y, false);
    A23 += __builtin_amdgcn_cvt_pk_f32_fp8(u2.y, true);
  }

  // Epilogue (fully unrolled, named scalars):
  // acc[d] = feat[d] + sum_e 0.5*tanh(mean_e[d]); then tanh, fp16 pack.
  const float inv = 1.f / NSEL;
  float v0 = ra.x + 0.5f * (fast_tanh(A00.x * inv) + fast_tanh(A10.x * inv) +
                            fast_tanh(A20.x * inv));
  float v1 = ra.y + 0.5f * (fast_tanh(A00.y * inv) + fast_tanh(A10.y * inv) +
                            fast_tanh(A20.y * inv));
  float v2 = ra.z + 0.5f * (fast_tanh(A01.x * inv) + fast_tanh(A11.x * inv) +
                            fast_tanh(A21.x * inv));
  float v3 = ra.w + 0.5f * (fast_tanh(A01.y * inv) + fast_tanh(A11.y * inv) +
                            fast_tanh(A21.y * inv));
  float v4 = rb.x + 0.5f * (fast_tanh(A02.x * inv) + fast_tanh(A12.x * inv) +
                            fast_tanh(A22.x * inv));
  float v5 = rb.y + 0.5f * (fast_tanh(A02.y * inv) + fast_tanh(A12.y * inv) +
                            fast_tanh(A22.y * inv));
  float v6 = rb.z + 0.5f * (fast_tanh(A03.x * inv) + fast_tanh(A13.x * inv) +
                            fast_tanh(A23.x * inv));
  float v7 = rb.w + 0.5f * (fast_tanh(A03.y * inv) + fast_tanh(A13.y * inv) +
                            fast_tanh(A23.y * inv));
  uint4 p;
  p.x = pack_h2(fast_tanh(v0), fast_tanh(v1));
  p.y = pack_h2(fast_tanh(v2), fast_tanh(v3));
  p.z = pack_h2(fast_tanh(v4), fast_tanh(v5));
  p.w = pack_h2(fast_tanh(v6), fast_tanh(v7));
  *(uint4*)(hfw + n * (D / 2) + sli * 4) = p;  // fp16 h row, 256 B/node
}

// Kernel C: out[50000x64] = h[50000x128] @ W_lin + b_lin via fp16 MFMA.
// h read fp16-packed from d_out rows, overwritten in place (each wave reads
// its full 16-row tile before storing). A: m=lane&15, k=(lane>>4)*8+j.
// C: n=lane&15, m=(lane>>4)*4+reg (m89-verified).
__global__ __launch_bounds__(256) void gemm_kernel(
    const unsigned int* __restrict__ hfw, const float* __restrict__ Wl,
    const float* __restrict__ bl, float* __restrict__ out) {
  __shared__ _Float16 sB[16 * 64 * 8];  // 16 KB: [kk*4+nt][lane][8]

  for (int w = threadIdx.x; w < 4096; w += blockDim.x) {
    int f = w >> 8, l = (w >> 2) & 63, j2 = w & 3;
    int kk = f >> 2, nt = f & 3;
    int k = kk * 32 + ((l >> 4) << 3) + 2 * j2;
    int nn = nt * 16 + (l & 15);
    ((unsigned int*)sB)[w] = pack_h2(Wl[k * DOUT + nn], Wl[(k + 1) * DOUT + nn]);
  }
  __syncthreads();

  const int lane = threadIdx.x & 63;
  const int tile = blockIdx.x * 4 + (threadIdx.x >> 6);
  if (tile >= NTILES) return;
  const int m0 = tile * 16;

  floatx4 acc[4];
#pragma unroll
  for (int nt = 0; nt < 4; ++nt) {
    float bn = bl[nt * 16 + (lane & 15)];
    acc[nt] = (floatx4){bn, bn, bn, bn};
  }
  const _Float16* hf = (const _Float16*)hfw;
#pragma unroll
  for (int kk = 0; kk < 4; ++kk) {
    half8 a = *(const half8*)(hf + (size_t)(m0 + (lane & 15)) * D + kk * 32 +
                              ((lane >> 4) << 3));
#pragma unroll
    for (int nt = 0; nt < 4; ++nt) {
      half8 bfr = *(const half8*)(sB + ((kk * 4 + nt) * 64 + lane) * 8);
      acc[nt] = __builtin_amdgcn_mfma_f32_16x16x32_f16(a, bfr, acc[nt], 0, 0, 0);
    }
  }
#pragma unroll
  for (int nt = 0; nt < 4; ++nt) {
#pragma unroll
    for (int r = 0; r < 4; ++r) {
      int m = m0 + ((lane >> 4) << 2) + r;
      out[(size_t)m * DOUT + nt * 16 + (lane & 15)] = acc[nt][r];
    }
  }
}

extern "C" void kernel_launch(void* const* d_in, const int* in_sizes, int n_in,
                              void* d_out, int out_size, void* d_ws,
                              size_t ws_size, hipStream_t stream) {
  const float* feat = (const float*)d_in[0];
  const float* Wm = (const float*)d_in[1];
  const float* bm = (const float*)d_in[2];
  const float* Wl = (const float*)d_in[3];
  const float* bl = (const float*)d_in[4];
  const int* nbr0 = (const int*)d_in[5];
  const int* nbr1 = (const int*)d_in[6];
  const int* nbr2 = (const int*)d_in[7];
  float* out = (float*)d_out;
  float2* mlp2 = (float2*)d_ws;                                       // 400 KB
  unsigned char* feat8 = (unsigned char*)d_ws + (512 << 10);          // 6.4 MB

  mlp_kernel<<<N_NODES / 8, 256, 0, stream>>>(feat, Wm, bm, mlp2, feat8);
  care_kernel<<<N_NODES / 16, 256, 0, stream>>>(feat, feat8, mlp2, nbr0, nbr1,
                                                nbr2, (unsigned int*)d_out);
  gemm_kernel<<<(NTILES + 3) / 4, 256, 0, stream>>>((const unsigned int*)d_out,
                                                    Wl, bl, out);
}

// Round 14
// 69.184 us; speedup vs baseline: 3.5488x; 3.4112x over previous
//
#include <hip/hip_runtime.h>
#include <hip/hip_fp16.h>

#define N_NODES 50000
#define K 32
#define NSEL 16
#define D 128
#define DOUT 64
#define NTILES (N_NODES / 16)  // 3125 MFMA node-tiles

typedef __attribute__((ext_vector_type(8))) _Float16 half8;
typedef __attribute__((ext_vector_type(4))) float floatx4;
typedef __attribute__((ext_vector_type(2))) float floatx2;

__device__ __forceinline__ unsigned int pack_h2(float a, float b) {
  union { __half2 h; unsigned int u; } c;
  c.h = __floats2half2_rn(a, b);
  return c.u;
}
__device__ __forceinline__ float fast_tanh(float x) {
  // 1 - 2/(1+e^{2x}). Exact at +/-inf.
  float e = __expf(2.f * x);
  return 1.f - __fdividef(2.f, 1.f + e);
}

// Kernel A: mlp2[n] = tanh(feat[n] @ W_mlp + b_mlp) (C=2), feat8 = fp8(feat).
// TWO nodes per wave. libm tanhf — mlp2 feeds top-k; fast tanh flips ties.
__global__ __launch_bounds__(256) void mlp_kernel(
    const float* __restrict__ feat, const float* __restrict__ Wm,
    const float* __restrict__ bm, float2* __restrict__ mlp2,
    unsigned char* __restrict__ feat8 /* [N][D] fp8 e4m3, 128 B rows */) {
  const int wid = (blockIdx.x * blockDim.x + threadIdx.x) >> 6;  // 0..24999
  const int lane = threadIdx.x & 63;
  const int sub = lane & 31;
  const int n = wid * 2 + (lane >> 5);

  float4 f = *(const float4*)(feat + (size_t)n * D + sub * 4);
  float4 w01 = *(const float4*)(Wm + sub * 8);
  float4 w23 = *(const float4*)(Wm + sub * 8 + 4);
  float p0 = f.x * w01.x + f.y * w01.z + f.z * w23.x + f.w * w23.z;
  float p1 = f.x * w01.y + f.y * w01.w + f.z * w23.y + f.w * w23.w;
#pragma unroll
  for (int off = 16; off; off >>= 1) {  // stays within the 32-lane half
    p0 += __shfl_xor(p0, off);
    p1 += __shfl_xor(p1, off);
  }
  int pk8 = __builtin_amdgcn_cvt_pk_fp8_f32(f.x, f.y, 0, false);
  pk8 = __builtin_amdgcn_cvt_pk_fp8_f32(f.z, f.w, pk8, true);
  *(unsigned int*)(feat8 + ((size_t)n << 7) + (sub << 2)) = (unsigned int)pk8;
  if (sub == 0) {
    mlp2[n] = make_float2(tanhf(p0 + bm[0]), tanhf(p1 + bm[1]));
  }
}

// Kernel B: TWO nodes per wave (R11 structure), but ALL cross-lane traffic
// via per-wave LDS tables + uniform-address broadcast ds_read_b128:
//   - dtab: 32 distance-bits per (half,etype); rank loop reads 4/b128.
//   - stab: rank-indexed (src<<7) table; gather reads 4 rows/b128.
// DS ops/thread: 147 (R11 bpermutes) -> 42. Selection keys u64
// (bits(d)<<32)|j — lexicographic < is EXACTLY top_k's tie-break.
// Accumulation order t=0..15 per etype — bit-identical to R11.
__global__ __launch_bounds__(256) void care_kernel(
    const float* __restrict__ feat, const unsigned char* __restrict__ feat8,
    const float2* __restrict__ mlp2, const int* __restrict__ nbr0,
    const int* __restrict__ nbr1, const int* __restrict__ nbr2,
    unsigned int* __restrict__ hfw /* aliases d_out; [N][64] words */) {
  __shared__ __align__(16) unsigned int dtab[4][2][3][32];  // 3 KB dist bits
  __shared__ __align__(16) unsigned int stab[4][2][3][16];  // 1.5 KB src<<7
  const int lane = threadIdx.x & 63;
  const int sub = lane & 31;
  const int h = lane >> 5;
  const int w = threadIdx.x >> 6;
  const int wid = (blockIdx.x * blockDim.x + threadIdx.x) >> 6;  // 0..24999
  const int n = wid * 2 + h;

  const float2 my = mlp2[n];
  float4 acc = *(const float4*)(feat + (size_t)n * D + sub * 4);  // residual

  // Phase 1: all edge ids + their mlp2 rows (6 loads in flight)
  const int src0 = nbr0[n * K + sub];
  const int src1 = nbr1[n * K + sub];
  const int src2 = nbr2[n * K + sub];
  const float2 mh0 = mlp2[src0];
  const float2 mh1 = mlp2[src1];
  const float2 mh2 = mlp2[src2];
  const unsigned b0 =
      (unsigned)__float_as_int(fabsf(mh0.x - my.x) + fabsf(mh0.y - my.y));
  const unsigned b1 =
      (unsigned)__float_as_int(fabsf(mh1.x - my.x) + fabsf(mh1.y - my.y));
  const unsigned b2 =
      (unsigned)__float_as_int(fabsf(mh2.x - my.x) + fabsf(mh2.y - my.y));
  dtab[w][h][0][sub] = b0;
  dtab[w][h][1][sub] = b1;
  dtab[w][h][2][sub] = b2;
  __builtin_amdgcn_wave_barrier();

  // Phase 2: rank = #{j : key_j < key_i}, key=(bits<<32)|j. Uniform b128
  // broadcast reads; j is a literal per unrolled step.
  const unsigned long long k0 = ((unsigned long long)b0 << 32) | (unsigned)sub;
  const unsigned long long k1 = ((unsigned long long)b1 << 32) | (unsigned)sub;
  const unsigned long long k2 = ((unsigned long long)b2 << 32) | (unsigned)sub;
  int c0 = 0, c1 = 0, c2 = 0;
#pragma unroll
  for (int q = 0; q < 8; ++q) {
    const uint4 q0 = *(const uint4*)&dtab[w][h][0][q * 4];
    const uint4 q1 = *(const uint4*)&dtab[w][h][1][q * 4];
    const uint4 q2 = *(const uint4*)&dtab[w][h][2][q * 4];
    c0 += (((unsigned long long)q0.x << 32) | (unsigned)(q * 4 + 0)) < k0;
    c0 += (((unsigned long long)q0.y << 32) | (unsigned)(q * 4 + 1)) < k0;
    c0 += (((unsigned long long)q0.z << 32) | (unsigned)(q * 4 + 2)) < k0;
    c0 += (((unsigned long long)q0.w << 32) | (unsigned)(q * 4 + 3)) < k0;
    c1 += (((unsigned long long)q1.x << 32) | (unsigned)(q * 4 + 0)) < k1;
    c1 += (((unsigned long long)q1.y << 32) | (unsigned)(q * 4 + 1)) < k1;
    c1 += (((unsigned long long)q1.z << 32) | (unsigned)(q * 4 + 2)) < k1;
    c1 += (((unsigned long long)q1.w << 32) | (unsigned)(q * 4 + 3)) < k1;
    c2 += (((unsigned long long)q2.x << 32) | (unsigned)(q * 4 + 0)) < k2;
    c2 += (((unsigned long long)q2.y << 32) | (unsigned)(q * 4 + 1)) < k2;
    c2 += (((unsigned long long)q2.z << 32) | (unsigned)(q * 4 + 2)) < k2;
    c2 += (((unsigned long long)q2.w << 32) | (unsigned)(q * 4 + 3)) < k2;
  }

  // Selection scatter: ranks are a permutation of 0..31 (keys distinct), so
  // exactly 16 lanes have c<16 and all 16 slots get written. Store src<<7
  // (pre-shifted fp8 row byte-offset).
  if (c0 < NSEL) stab[w][h][0][c0] = (unsigned)src0 << 7;
  if (c1 < NSEL) stab[w][h][1][c1] = (unsigned)src1 << 7;
  if (c2 < NSEL) stab[w][h][2][c2] = (unsigned)src2 << 7;
  __builtin_amdgcn_wave_barrier();

  // Phase 3: gather — per quad: 3 uniform b128 sel reads, then 12
  // independent dword fp8 loads; packed f32 accumulation in t-order.
  const unsigned off4 = (unsigned)sub << 2;
  floatx2 A00 = {0.f, 0.f}, A01 = {0.f, 0.f};
  floatx2 A10 = {0.f, 0.f}, A11 = {0.f, 0.f};
  floatx2 A20 = {0.f, 0.f}, A21 = {0.f, 0.f};
#pragma unroll
  for (int q = 0; q < 4; ++q) {
    const uint4 s0 = *(const uint4*)&stab[w][h][0][q * 4];
    const uint4 s1 = *(const uint4*)&stab[w][h][1][q * 4];
    const uint4 s2 = *(const uint4*)&stab[w][h][2][q * 4];
    const unsigned w00 = *(const unsigned*)(feat8 + (s0.x | off4));
    const unsigned w01 = *(const unsigned*)(feat8 + (s0.y | off4));
    const unsigned w02 = *(const unsigned*)(feat8 + (s0.z | off4));
    const unsigned w03 = *(const unsigned*)(feat8 + (s0.w | off4));
    const unsigned w10 = *(const unsigned*)(feat8 + (s1.x | off4));
    const unsigned w11 = *(const unsigned*)(feat8 + (s1.y | off4));
    const unsigned w12 = *(const unsigned*)(feat8 + (s1.z | off4));
    const unsigned w13 = *(const unsigned*)(feat8 + (s1.w | off4));
    const unsigned w20 = *(const unsigned*)(feat8 + (s2.x | off4));
    const unsigned w21 = *(const unsigned*)(feat8 + (s2.y | off4));
    const unsigned w22 = *(const unsigned*)(feat8 + (s2.z | off4));
    const unsigned w23 = *(const unsigned*)(feat8 + (s2.w | off4));
    // t-order within quad: .x, .y, .z, .w  (bit-identical to R11)
    A00 += __builtin_amdgcn_cvt_pk_f32_fp8(w00, false);
    A01 += __builtin_amdgcn_cvt_pk_f32_fp8(w00, true);
    A00 += __builtin_amdgcn_cvt_pk_f32_fp8(w01, false);
    A01 += __builtin_amdgcn_cvt_pk_f32_fp8(w01, true);
    A00 += __builtin_amdgcn_cvt_pk_f32_fp8(w02, false);
    A01 += __builtin_amdgcn_cvt_pk_f32_fp8(w02, true);
    A00 += __builtin_amdgcn_cvt_pk_f32_fp8(w03, false);
    A01 += __builtin_amdgcn_cvt_pk_f32_fp8(w03, true);
    A10 += __builtin_amdgcn_cvt_pk_f32_fp8(w10, false);
    A11 += __builtin_amdgcn_cvt_pk_f32_fp8(w10, true);
    A10 += __builtin_amdgcn_cvt_pk_f32_fp8(w11, false);
    A11 += __builtin_amdgcn_cvt_pk_f32_fp8(w11, true);
    A10 += __builtin_amdgcn_cvt_pk_f32_fp8(w12, false);
    A11 += __builtin_amdgcn_cvt_pk_f32_fp8(w12, true);
    A10 += __builtin_amdgcn_cvt_pk_f32_fp8(w13, false);
    A11 += __builtin_amdgcn_cvt_pk_f32_fp8(w13, true);
    A20 += __builtin_amdgcn_cvt_pk_f32_fp8(w20, false);
    A21 += __builtin_amdgcn_cvt_pk_f32_fp8(w20, true);
    A20 += __builtin_amdgcn_cvt_pk_f32_fp8(w21, false);
    A21 += __builtin_amdgcn_cvt_pk_f32_fp8(w21, true);
    A20 += __builtin_amdgcn_cvt_pk_f32_fp8(w22, false);
    A21 += __builtin_amdgcn_cvt_pk_f32_fp8(w22, true);
    A20 += __builtin_amdgcn_cvt_pk_f32_fp8(w23, false);
    A21 += __builtin_amdgcn_cvt_pk_f32_fp8(w23, true);
  }
  acc.x += 0.5f * fast_tanh(A00.x * (1.f / NSEL));
  acc.y += 0.5f * fast_tanh(A00.y * (1.f / NSEL));
  acc.z += 0.5f * fast_tanh(A01.x * (1.f / NSEL));
  acc.w += 0.5f * fast_tanh(A01.y * (1.f / NSEL));
  acc.x += 0.5f * fast_tanh(A10.x * (1.f / NSEL));
  acc.y += 0.5f * fast_tanh(A10.y * (1.f / NSEL));
  acc.z += 0.5f * fast_tanh(A11.x * (1.f / NSEL));
  acc.w += 0.5f * fast_tanh(A11.y * (1.f / NSEL));
  acc.x += 0.5f * fast_tanh(A20.x * (1.f / NSEL));
  acc.y += 0.5f * fast_tanh(A20.y * (1.f / NSEL));
  acc.z += 0.5f * fast_tanh(A21.x * (1.f / NSEL));
  acc.w += 0.5f * fast_tanh(A21.y * (1.f / NSEL));

  acc.x = fast_tanh(acc.x);
  acc.y = fast_tanh(acc.y);
  acc.z = fast_tanh(acc.z);
  acc.w = fast_tanh(acc.w);
  uint2 p;
  p.x = pack_h2(acc.x, acc.y);
  p.y = pack_h2(acc.z, acc.w);
  *(uint2*)(hfw + n * (D / 2) + sub * 2) = p;  // fp16 h row, 256 B/node
}

// Kernel C: out[50000x64] = h[50000x128] @ W_lin + b_lin via fp16 MFMA.
// h read fp16-packed from d_out rows, overwritten in place (each wave reads
// its full 16-row tile before storing). A: m=lane&15, k=(lane>>4)*8+j.
// C: n=lane&15, m=(lane>>4)*4+reg (m89-verified).
__global__ __launch_bounds__(256) void gemm_kernel(
    const unsigned int* __restrict__ hfw, const float* __restrict__ Wl,
    const float* __restrict__ bl, float* __restrict__ out) {
  __shared__ _Float16 sB[16 * 64 * 8];  // 16 KB: [kk*4+nt][lane][8]

  for (int w = threadIdx.x; w < 4096; w += blockDim.x) {
    int f = w >> 8, l = (w >> 2) & 63, j2 = w & 3;
    int kk = f >> 2, nt = f & 3;
    int k = kk * 32 + ((l >> 4) << 3) + 2 * j2;
    int nn = nt * 16 + (l & 15);
    ((unsigned int*)sB)[w] = pack_h2(Wl[k * DOUT + nn], Wl[(k + 1) * DOUT + nn]);
  }
  __syncthreads();

  const int lane = threadIdx.x & 63;
  const int tile = blockIdx.x * 4 + (threadIdx.x >> 6);
  if (tile >= NTILES) return;
  const int m0 = tile * 16;

  floatx4 acc[4];
#pragma unroll
  for (int nt = 0; nt < 4; ++nt) {
    float bn = bl[nt * 16 + (lane & 15)];
    acc[nt] = (floatx4){bn, bn, bn, bn};
  }
  const _Float16* hf = (const _Float16*)hfw;
#pragma unroll
  for (int kk = 0; kk < 4; ++kk) {
    half8 a = *(const half8*)(hf + (size_t)(m0 + (lane & 15)) * D + kk * 32 +
                              ((lane >> 4) << 3));
#pragma unroll
    for (int nt = 0; nt < 4; ++nt) {
      half8 bfr = *(const half8*)(sB + ((kk * 4 + nt) * 64 + lane) * 8);
      acc[nt] = __builtin_amdgcn_mfma_f32_16x16x32_f16(a, bfr, acc[nt], 0, 0, 0);
    }
  }
#pragma unroll
  for (int nt = 0; nt < 4; ++nt) {
#pragma unroll
    for (int r = 0; r < 4; ++r) {
      int m = m0 + ((lane >> 4) << 2) + r;
      out[(size_t)m * DOUT + nt * 16 + (lane & 15)] = acc[nt][r];
    }
  }
}

extern "C" void kernel_launch(void* const* d_in, const int* in_sizes, int n_in,
                              void* d_out, int out_size, void* d_ws,
                              size_t ws_size, hipStream_t stream) {
  const float* feat = (const float*)d_in[0];
  const float* Wm = (const float*)d_in[1];
  const float* bm = (const float*)d_in[2];
  const float* Wl = (const float*)d_in[3];
  const float* bl = (const float*)d_in[4];
  const int* nbr0 = (const int*)d_in[5];
  const int* nbr1 = (const int*)d_in[6];
  const int* nbr2 = (const int*)d_in[7];
  float* out = (float*)d_out;
  float2* mlp2 = (float2*)d_ws;                                       // 400 KB
  unsigned char* feat8 = (unsigned char*)d_ws + (512 << 10);          // 6.4 MB

  mlp_kernel<<<N_NODES / 8, 256, 0, stream>>>(feat, Wm, bm, mlp2, feat8);
  care_kernel<<<N_NODES / 8, 256, 0, stream>>>(feat, feat8, mlp2, nbr0, nbr1,
                                               nbr2, (unsigned int*)d_out);
  gemm_kernel<<<(NTILES + 3) / 4, 256, 0, stream>>>((const unsigned int*)d_out,
                                                    Wl, bl, out);
}